// Round 1
// baseline (4108.770 us; speedup 1.0000x reference)
//
#include <hip/hip_runtime.h>
#include <math.h>

#define N_TOK 13824   // 24*24*24
#define CCH   256     // C
#define CQ    32      // C_ = C/8

// ---------------------------------------------------------------------------
// Kernel 1: projections  g = x@wg+bg [N,32], f = x@wf+bf [N,32], h = x@wh+bh [N,256]
// One block = 8 token rows, 256 threads.
// ---------------------------------------------------------------------------
__global__ __launch_bounds__(256) void proj_kernel(
    const float* __restrict__ x,
    const float* __restrict__ wg, const float* __restrict__ bg,
    const float* __restrict__ wf, const float* __restrict__ bf,
    const float* __restrict__ wh, const float* __restrict__ bh,
    float* __restrict__ g, float* __restrict__ f, float* __restrict__ h)
{
    __shared__ float xs[8][CCH];
    const int t = threadIdx.x;
    const int row0 = blockIdx.x * 8;

    #pragma unroll
    for (int r = 0; r < 8; ++r)
        xs[r][t] = x[(row0 + r) * CCH + t];
    __syncthreads();

    // h projection: thread t owns output channel t for all 8 rows
    float acc[8];
    #pragma unroll
    for (int r = 0; r < 8; ++r) acc[r] = bh[t];
    for (int k = 0; k < CCH; ++k) {
        float w = wh[k * CCH + t];
        #pragma unroll
        for (int r = 0; r < 8; ++r) acc[r] += xs[r][k] * w;
    }
    #pragma unroll
    for (int r = 0; r < 8; ++r) h[(row0 + r) * CCH + t] = acc[r];

    // g/f projections: threads 0..31 -> g channel t, 32..63 -> f channel t-32
    if (t < 64) {
        const int c = t & 31;
        const bool is_g = (t < 32);
        const float* w = is_g ? wg : wf;
        const float  b = is_g ? bg[c] : bf[c];
        float a2[8];
        #pragma unroll
        for (int r = 0; r < 8; ++r) a2[r] = b;
        for (int k = 0; k < CCH; ++k) {
            float wv = w[k * CQ + c];
            #pragma unroll
            for (int r = 0; r < 8; ++r) a2[r] += xs[r][k] * wv;
        }
        float* o = is_g ? g : f;
        #pragma unroll
        for (int r = 0; r < 8; ++r) o[(row0 + r) * CQ + c] = a2[r];
    }
}

// ---------------------------------------------------------------------------
// Kernel 2: flash attention, fp32.
// Block = 256 threads, owns QT=32 queries. Key tiles of KT=64.
// Thread t accumulates output channel t for all 32 queries (32 regs).
// ---------------------------------------------------------------------------
__global__ __launch_bounds__(256) void attn_kernel(
    const float* __restrict__ g,   // Q [N, 32]
    const float* __restrict__ f,   // K [N, 32]
    const float* __restrict__ h,   // V [N, 256]
    const float* __restrict__ x,
    const float* __restrict__ gamma,
    float* __restrict__ out)
{
    __shared__ float            qs[32][CQ];       // Q tile
    __shared__ float            ks[64][36];       // K tile, pad 32->36 (16B-aligned rows, spreads banks)
    __shared__ __align__(16) float ps[32][64];    // scores / probabilities
    __shared__ float m_s[32], l_s[32], r_s[32];

    const int t  = threadIdx.x;
    const int q0 = blockIdx.x * 32;
    const int wv = t >> 6;    // wave id 0..3
    const int jl = t & 63;    // key lane within tile

    // stage Q tile (32*32 floats, 4 per thread)
    #pragma unroll
    for (int i = t; i < 32 * CQ; i += 256)
        qs[i >> 5][i & 31] = g[q0 * CQ + i];
    if (t < 32) { m_s[t] = -INFINITY; l_s[t] = 0.f; }

    float acc[32];
    #pragma unroll
    for (int q = 0; q < 32; ++q) acc[q] = 0.f;

    const int qrow = t >> 3;   // 0..31 (for softmax phase)
    const int part = t & 7;    // 0..7

    for (int k0 = 0; k0 < N_TOK; k0 += 64) {
        __syncthreads();   // prev PV done, Q staged (first iter)
        // stage K tile: 64*32 floats, 8 per thread
        #pragma unroll
        for (int i = t; i < 64 * CQ; i += 256)
            ks[i >> 5][i & 31] = f[k0 * CQ + i];
        __syncthreads();

        // scores: wave wv computes rows 8*wv..8*wv+7, lane jl = key index
        {
            float s[8];
            #pragma unroll
            for (int i = 0; i < 8; ++i) s[i] = 0.f;
            #pragma unroll
            for (int kk = 0; kk < CQ; kk += 4) {
                float4 kv = *(const float4*)&ks[jl][kk];
                #pragma unroll
                for (int i = 0; i < 8; ++i) {
                    float4 qv = *(const float4*)&qs[wv * 8 + i][kk];
                    s[i] += qv.x * kv.x + qv.y * kv.y + qv.z * kv.z + qv.w * kv.w;
                }
            }
            #pragma unroll
            for (int i = 0; i < 8; ++i) ps[wv * 8 + i][jl] = s[i];
        }
        __syncthreads();

        // online softmax: 8 threads per query row
        {
            float mx = -INFINITY;
            #pragma unroll
            for (int jj = 0; jj < 8; ++jj)
                mx = fmaxf(mx, ps[qrow][part + 8 * jj]);
            #pragma unroll
            for (int w = 1; w < 8; w <<= 1)
                mx = fmaxf(mx, __shfl_xor(mx, w));
            const float m_old = m_s[qrow];
            const float m_new = fmaxf(m_old, mx);
            float sum = 0.f;
            #pragma unroll
            for (int jj = 0; jj < 8; ++jj) {
                float p = __expf(ps[qrow][part + 8 * jj] - m_new);
                ps[qrow][part + 8 * jj] = p;
                sum += p;
            }
            #pragma unroll
            for (int w = 1; w < 8; w <<= 1)
                sum += __shfl_xor(sum, w);
            if (part == 0) {
                const float r = __expf(m_old - m_new);
                r_s[qrow] = r;
                l_s[qrow] = l_s[qrow] * r + sum;
                m_s[qrow] = m_new;
            }
        }
        __syncthreads();

        // rescale + PV: thread t = channel t
        #pragma unroll
        for (int q = 0; q < 32; ++q) acc[q] *= r_s[q];
        for (int j0 = 0; j0 < 64; j0 += 4) {
            const float v0 = h[(k0 + j0 + 0) * CCH + t];
            const float v1 = h[(k0 + j0 + 1) * CCH + t];
            const float v2 = h[(k0 + j0 + 2) * CCH + t];
            const float v3 = h[(k0 + j0 + 3) * CCH + t];
            #pragma unroll
            for (int q = 0; q < 32; ++q) {
                float4 p = *(const float4*)&ps[q][j0];
                acc[q] += p.x * v0 + p.y * v1 + p.z * v2 + p.w * v3;
            }
        }
    }
    __syncthreads();

    // epilogue: out = gamma * (acc/l) + x
    const float gm = gamma[t];
    #pragma unroll
    for (int q = 0; q < 32; ++q) {
        const int row = q0 + q;
        out[row * CCH + t] = gm * (acc[q] / l_s[q]) + x[row * CCH + t];
    }
}

// ---------------------------------------------------------------------------
extern "C" void kernel_launch(void* const* d_in, const int* in_sizes, int n_in,
                              void* d_out, int out_size, void* d_ws, size_t ws_size,
                              hipStream_t stream) {
    const float* x     = (const float*)d_in[0];
    const float* wg    = (const float*)d_in[1];
    const float* bg    = (const float*)d_in[2];
    const float* wf    = (const float*)d_in[3];
    const float* bf    = (const float*)d_in[4];
    const float* wh    = (const float*)d_in[5];
    const float* bh    = (const float*)d_in[6];
    const float* gamma = (const float*)d_in[7];
    float* out = (float*)d_out;

    float* ws = (float*)d_ws;
    float* g  = ws;                      // [N, 32]
    float* f  = ws + (size_t)N_TOK * CQ; // [N, 32]
    float* h  = ws + (size_t)2 * N_TOK * CQ; // [N, 256]

    proj_kernel<<<N_TOK / 8, 256, 0, stream>>>(x, wg, bg, wf, bf, wh, bh, g, f, h);
    attn_kernel<<<N_TOK / 32, 256, 0, stream>>>(g, f, h, x, gamma, out);
}

// Round 2
// 484.681 us; speedup vs baseline: 8.4773x; 8.4773x over previous
//
#include <hip/hip_runtime.h>
#include <hip/hip_bf16.h>
#include <math.h>

#define N_TOK 13824
#define NT    216        // N_TOK / 64 key tiles

typedef __attribute__((ext_vector_type(8))) short bf16x8;
typedef __attribute__((ext_vector_type(4))) float f32x4;
typedef unsigned short u16;

#define AS3(p) ((__attribute__((address_space(3))) void*)(p))
#define AS1(p) ((const __attribute__((address_space(1))) void*)(p))
#define GLL(gp, lp) __builtin_amdgcn_global_load_lds(AS1(gp), AS3(lp), 16, 0, 0)

__device__ inline u16 f2b(float v) {
    union { float f; unsigned u; } a; a.f = v;
    unsigned r = a.u + 0x7fffu + ((a.u >> 16) & 1u);   // round-to-nearest-even
    return (u16)(r >> 16);
}

// ---------------------------------------------------------------------------
// Kernel 0: x -> bf16; weights -> WcatT [320 n][256 k] bf16 (n: 0..255=wh col,
// 256..287=wg col, 288..319=wf col)
// ---------------------------------------------------------------------------
__global__ __launch_bounds__(512) void prep_kernel(
    const float* __restrict__ x, const float* __restrict__ wh,
    const float* __restrict__ wg, const float* __restrict__ wf,
    u16* __restrict__ xb, u16* __restrict__ wt)
{
    int id = blockIdx.x * 512 + threadIdx.x;
    if (id < N_TOK * 256 / 4) {
        float4 v = ((const float4*)x)[id];
        ushort4 o;
        o.x = f2b(v.x); o.y = f2b(v.y); o.z = f2b(v.z); o.w = f2b(v.w);
        ((ushort4*)xb)[id] = o;
    }
    if (id < 320 * 256) {
        int n = id >> 8, k = id & 255;
        float v = (n < 256) ? wh[k * 256 + n]
                : (n < 288) ? wg[k * 32 + (n - 256)]
                            : wf[k * 32 + (n - 288)];
        wt[n * 256 + k] = f2b(v);
    }
}

// ---------------------------------------------------------------------------
// Kernel 1: proj GEMM  [13824,256] x [256,320] -> g[.,32] f[.,32] h[.,256] bf16
// 64x64 tiles, 4 waves, T2-XOR-swizzled LDS (pre-swizzled global source).
// ---------------------------------------------------------------------------
__global__ __launch_bounds__(256) void proj_kernel(
    const u16* __restrict__ xb, const u16* __restrict__ wt,
    const float* __restrict__ bg, const float* __restrict__ bfv, const float* __restrict__ bh,
    u16* __restrict__ g, u16* __restrict__ f, u16* __restrict__ h)
{
    __shared__ u16 As[64 * 64];
    __shared__ u16 Bs[64 * 64];
    const int t = threadIdx.x, l = t & 63, w = t >> 6;
    const int m0 = blockIdx.x * 64, n0 = blockIdx.y * 64;
    const int mh = (w & 1) * 32, nh = (w >> 1) * 32;
    f32x4 acc[2][2] = {};

    for (int kstep = 0; kstep < 4; ++kstep) {
        const int k0 = kstep * 64;
        __syncthreads();
        #pragma unroll
        for (int i = 0; i < 2; ++i) {
            int ch  = w * 2 + i;                 // 8-row chunk
            int row = ch * 8 + (l >> 3);
            int ul  = (l & 7) ^ ((l >> 3) & 7);  // swizzled source 16B unit
            GLL(xb + (size_t)(m0 + row) * 256 + k0 + ul * 8, As + ch * 512);
            GLL(wt + (size_t)(n0 + row) * 256 + k0 + ul * 8, Bs + ch * 512);
        }
        asm volatile("s_waitcnt vmcnt(0)" ::: "memory");
        __syncthreads();
        #pragma unroll
        for (int ks = 0; ks < 2; ++ks) {
            bf16x8 a[2], b[2];
            #pragma unroll
            for (int mf = 0; mf < 2; ++mf) {
                int row = mh + mf * 16 + (l & 15);
                int u   = (ks * 4 + (l >> 4)) ^ (row & 7);
                a[mf] = *(const bf16x8*)(As + row * 64 + u * 8);
            }
            #pragma unroll
            for (int nf = 0; nf < 2; ++nf) {
                int row = nh + nf * 16 + (l & 15);
                int u   = (ks * 4 + (l >> 4)) ^ (row & 7);
                b[nf] = *(const bf16x8*)(Bs + row * 64 + u * 8);
            }
            #pragma unroll
            for (int mf = 0; mf < 2; ++mf)
                #pragma unroll
                for (int nf = 0; nf < 2; ++nf)
                    acc[mf][nf] = __builtin_amdgcn_mfma_f32_16x16x32_bf16(
                        a[mf], b[nf], acc[mf][nf], 0, 0, 0);
        }
    }

    #pragma unroll
    for (int mf = 0; mf < 2; ++mf)
        #pragma unroll
        for (int nf = 0; nf < 2; ++nf)
            #pragma unroll
            for (int r = 0; r < 4; ++r) {
                int row = m0 + mh + mf * 16 + (l >> 4) * 4 + r;
                int col = n0 + nh + nf * 16 + (l & 15);
                float bias = (col < 256) ? bh[col] : (col < 288) ? bg[col - 256] : bfv[col - 288];
                u16 v = f2b(acc[mf][nf][r] + bias);
                if (col < 256)      h[(size_t)row * 256 + col] = v;
                else if (col < 288) g[(size_t)row * 32 + (col - 256)] = v;
                else                f[(size_t)row * 32 + (col - 288)] = v;
            }
}

// ---------------------------------------------------------------------------
// Kernel 2: MFMA flash attention. 216 blocks x 512 thr (8 waves).
// wave w: qf = w&3 (16 q rows), chh = w>>2 (128-channel half).
// KT=64 keys/tile; K linear LDS, V subtiled LDS (tr_b16 reads), both via
// global_load_lds, double-buffered with counted vmcnt.
// ---------------------------------------------------------------------------
__global__ __launch_bounds__(512) void attn_kernel(
    const u16* __restrict__ g, const u16* __restrict__ f, const u16* __restrict__ h,
    const float* __restrict__ x, const float* __restrict__ gamma, float* __restrict__ out)
{
    __shared__ u16 Vt[2][16384];   // 2 x 32KB: subtiles s=(j>>2)*16+(c>>4); idx=s*64+(j&3)*16+(c&15)
    __shared__ u16 Ks[2][2048];    // 2 x 4KB:  [key][32] linear
    __shared__ u16 Ps[8][1152];    // per-wave P [16 q][72 j]

    const int t = threadIdx.x, l = t & 63, w = t >> 6;
    const int qf = w & 3, chh = w >> 2;
    const int q0 = blockIdx.x * 64;
    const int l15 = l & 15, lg = l >> 4;

    bf16x8 qa = *(const bf16x8*)(g + (size_t)(q0 + qf * 16 + l15) * 32 + lg * 8);

    float m_run[4], l_run[4];
    f32x4 acc[8] = {};
    #pragma unroll
    for (int r = 0; r < 4; ++r) { m_run[r] = -1e30f; l_run[r] = 0.f; }

    auto stage = [&](int tile, int buf) {
        const int k0 = tile * 64;
        #pragma unroll
        for (int i = 0; i < 4; ++i) {
            int cch = w * 4 + i;                       // 1KB LDS chunk
            int s   = cch * 8 + (l >> 3);              // subtile index
            int j   = (s >> 4) * 4 + ((l & 7) >> 1);
            int cc  = (s & 15) * 16 + (l & 1) * 8;
            GLL(h + (size_t)(k0 + j) * 256 + cc, &Vt[buf][cch * 512]);
        }
        if (w < 4)
            GLL(f + (size_t)(k0 + w * 16 + (l >> 2)) * 32 + (l & 3) * 8, &Ks[buf][w * 512]);
    };

    stage(0, 0);

    for (int tl = 0; tl < NT; ++tl) {
        const int buf = tl & 1;
        __builtin_amdgcn_s_barrier();                  // all waves done with buf^1
        stage(tl + 1 < NT ? tl + 1 : 0, buf ^ 1);      // prefetch next tile (async)
        if (w < 4) asm volatile("s_waitcnt vmcnt(5)" ::: "memory");
        else       asm volatile("s_waitcnt vmcnt(4)" ::: "memory");
        __builtin_amdgcn_s_barrier();                  // tile tl fully staged

        // ---- S = Q K^T : 4 x mfma(16x16x32) ----
        f32x4 sf[4];
        #pragma unroll
        for (int kf = 0; kf < 4; ++kf) {
            bf16x8 kb = *(const bf16x8*)(&Ks[buf][(kf * 16 + l15) * 32 + lg * 8]);
            f32x4 z = {};
            sf[kf] = __builtin_amdgcn_mfma_f32_16x16x32_bf16(qa, kb, z, 0, 0, 0);
        }

        // ---- online softmax (row r lives in reg r of lane-group lg) ----
        float p[4][4], rf[4];
        #pragma unroll
        for (int r = 0; r < 4; ++r) {
            float mx = fmaxf(fmaxf(sf[0][r], sf[1][r]), fmaxf(sf[2][r], sf[3][r]));
            mx = fmaxf(mx, __shfl_xor(mx, 1));
            mx = fmaxf(mx, __shfl_xor(mx, 2));
            mx = fmaxf(mx, __shfl_xor(mx, 4));
            mx = fmaxf(mx, __shfl_xor(mx, 8));
            float mnew = fmaxf(m_run[r], mx);
            float sum = 0.f;
            #pragma unroll
            for (int kf = 0; kf < 4; ++kf) { p[r][kf] = __expf(sf[kf][r] - mnew); sum += p[r][kf]; }
            sum += __shfl_xor(sum, 1);
            sum += __shfl_xor(sum, 2);
            sum += __shfl_xor(sum, 4);
            sum += __shfl_xor(sum, 8);
            rf[r]    = __expf(m_run[r] - mnew);
            l_run[r] = l_run[r] * rf[r] + sum;
            m_run[r] = mnew;
        }
        #pragma unroll
        for (int c0 = 0; c0 < 8; ++c0)
            #pragma unroll
            for (int r = 0; r < 4; ++r) acc[c0][r] *= rf[r];

        // ---- P -> per-wave LDS (bf16) ----
        #pragma unroll
        for (int r = 0; r < 4; ++r)
            #pragma unroll
            for (int kf = 0; kf < 4; ++kf)
                Ps[w][(lg * 4 + r) * 72 + kf * 16 + l15] = f2b(p[r][kf]);
        asm volatile("s_waitcnt lgkmcnt(0)" ::: "memory");
        __builtin_amdgcn_sched_barrier(0);

        // ---- PV : A = P (LDS b128), B = V (tr_b16 pairs) ----
        unsigned vbase = (unsigned)(size_t)AS3(&Vt[buf][0]) + lg * 4096 + l15 * 2 + chh * 1024;
        #pragma unroll
        for (int js = 0; js < 2; ++js) {
            bf16x8 pa = *(const bf16x8*)(&Ps[w][l15 * 72 + js * 32 + lg * 8]);
            unsigned long long lo[8], hi[8];
            #pragma unroll
            for (int c0 = 0; c0 < 8; ++c0) {
                unsigned va = vbase + js * 16384 + c0 * 128;
                asm volatile("ds_read_b64_tr_b16 %0, %2\n\t"
                             "ds_read_b64_tr_b16 %1, %2 offset:2048"
                             : "=v"(lo[c0]), "=v"(hi[c0]) : "v"(va));
            }
            asm volatile("s_waitcnt lgkmcnt(0)" ::: "memory");
            __builtin_amdgcn_sched_barrier(0);
            #pragma unroll
            for (int c0 = 0; c0 < 8; ++c0) {
                union { unsigned long long q[2]; bf16x8 v; } vb;
                vb.q[0] = lo[c0]; vb.q[1] = hi[c0];
                acc[c0] = __builtin_amdgcn_mfma_f32_16x16x32_bf16(pa, vb.v, acc[c0], 0, 0, 0);
            }
        }
    }

    // ---- epilogue: out = gamma * (acc/l) + x ----
    #pragma unroll
    for (int r = 0; r < 4; ++r) l_run[r] = 1.f / l_run[r];
    const int orow = q0 + qf * 16 + lg * 4;
    #pragma unroll
    for (int c0 = 0; c0 < 8; ++c0) {
        int col = chh * 128 + c0 * 16 + l15;
        float gm = gamma[col];
        #pragma unroll
        for (int r = 0; r < 4; ++r) {
            size_t idx = (size_t)(orow + r) * 256 + col;
            out[idx] = gm * (acc[c0][r] * l_run[r]) + x[idx];
        }
    }
}

// ---------------------------------------------------------------------------
extern "C" void kernel_launch(void* const* d_in, const int* in_sizes, int n_in,
                              void* d_out, int out_size, void* d_ws, size_t ws_size,
                              hipStream_t stream) {
    const float* x     = (const float*)d_in[0];
    const float* wg    = (const float*)d_in[1];
    const float* bg    = (const float*)d_in[2];
    const float* wf    = (const float*)d_in[3];
    const float* bfv   = (const float*)d_in[4];
    const float* wh    = (const float*)d_in[5];
    const float* bh    = (const float*)d_in[6];
    const float* gamma = (const float*)d_in[7];
    float* out = (float*)d_out;

    u16* ws = (u16*)d_ws;
    u16* xb = ws;                         // 13824*256
    u16* wt = xb + (size_t)N_TOK * 256;   // 320*256
    u16* gq = wt + 320 * 256;             // 13824*32
    u16* fk = gq + (size_t)N_TOK * 32;    // 13824*32
    u16* hv = fk + (size_t)N_TOK * 32;    // 13824*256

    prep_kernel<<<1728, 512, 0, stream>>>(x, wh, wg, wf, xb, wt);
    proj_kernel<<<dim3(216, 5), 256, 0, stream>>>(xb, wt, bg, bfv, bh, gq, fk, hv);
    attn_kernel<<<216, 512, 0, stream>>>(gq, fk, hv, x, gamma, out);
}

// Round 3
// 205.769 us; speedup vs baseline: 19.9679x; 2.3555x over previous
//
#include <hip/hip_runtime.h>
#include <math.h>

#define N_TOK 13824
#define KT 32
#define NSPLIT 4
#define KEYS_PER_SPLIT (N_TOK / NSPLIT)        // 3456
#define TILES_PER_SPLIT (KEYS_PER_SPLIT / KT)  // 108

typedef __attribute__((ext_vector_type(8)))  short bf16x8;
typedef __attribute__((ext_vector_type(4)))  float f32x4;
typedef __attribute__((ext_vector_type(16))) float f32x16;
typedef unsigned short u16;

#define AS3(p) ((__attribute__((address_space(3))) void*)(p))
#define AS1(p) ((const __attribute__((address_space(1))) void*)(p))
#define GLL(gp, lp) __builtin_amdgcn_global_load_lds(AS1(gp), AS3(lp), 16, 0, 0)

__device__ inline u16 f2b(float v) {
    union { float f; unsigned u; } a; a.f = v;
    unsigned r = a.u + 0x7fffu + ((a.u >> 16) & 1u);
    return (u16)(r >> 16);
}
__device__ inline float b2f(u16 v) {
    union { unsigned u; float f; } a; a.u = ((unsigned)v) << 16; return a.f;
}
// cross 32-lane-half combine: returns op(own, partner) in ALL lanes
__device__ inline float cross_max(float v) {
    float a = v, b = v;
    asm volatile("v_permlane32_swap_b32 %0, %1" : "+v"(a), "+v"(b));
    return fmaxf(a, b);
}
__device__ inline float cross_sum(float v) {
    float a = v, b = v;
    asm volatile("v_permlane32_swap_b32 %0, %1" : "+v"(a), "+v"(b));
    return a + b;
}
__device__ inline unsigned cvtpk(float lo, float hi) {
    unsigned r;
    asm volatile("v_cvt_pk_bf16_f32 %0, %1, %2" : "=v"(r) : "v"(lo), "v"(hi));
    return r;
}

// ---------------------------------------------------------------------------
// Kernel 0: x -> bf16; weights -> WcatT [320 n][256 k] bf16
// ---------------------------------------------------------------------------
__global__ __launch_bounds__(512) void prep_kernel(
    const float* __restrict__ x, const float* __restrict__ wh,
    const float* __restrict__ wg, const float* __restrict__ wf,
    u16* __restrict__ xb, u16* __restrict__ wt)
{
    int id = blockIdx.x * 512 + threadIdx.x;
    if (id < N_TOK * 256 / 4) {
        float4 v = ((const float4*)x)[id];
        ushort4 o;
        o.x = f2b(v.x); o.y = f2b(v.y); o.z = f2b(v.z); o.w = f2b(v.w);
        ((ushort4*)xb)[id] = o;
    }
    if (id < 320 * 256) {
        int n = id >> 8, k = id & 255;
        float v = (n < 256) ? wh[k * 256 + n]
                : (n < 288) ? wg[k * 32 + (n - 256)]
                            : wf[k * 32 + (n - 288)];
        wt[n * 256 + k] = f2b(v);
    }
}

// ---------------------------------------------------------------------------
// Kernel 1: proj GEMM  [13824,256] x [256,320] -> g[.,32] f[.,32] h[.,256] bf16
// ---------------------------------------------------------------------------
__global__ __launch_bounds__(256) void proj_kernel(
    const u16* __restrict__ xb, const u16* __restrict__ wt,
    const float* __restrict__ bg, const float* __restrict__ bfv, const float* __restrict__ bh,
    u16* __restrict__ g, u16* __restrict__ f, u16* __restrict__ h)
{
    __shared__ u16 As[64 * 64];
    __shared__ u16 Bs[64 * 64];
    const int t = threadIdx.x, l = t & 63, w = t >> 6;
    const int m0 = blockIdx.x * 64, n0 = blockIdx.y * 64;
    const int mh = (w & 1) * 32, nh = (w >> 1) * 32;
    f32x4 acc[2][2] = {};

    for (int kstep = 0; kstep < 4; ++kstep) {
        const int k0 = kstep * 64;
        __syncthreads();
        #pragma unroll
        for (int i = 0; i < 2; ++i) {
            int ch  = w * 2 + i;
            int row = ch * 8 + (l >> 3);
            int ul  = (l & 7) ^ ((l >> 3) & 7);
            GLL(xb + (size_t)(m0 + row) * 256 + k0 + ul * 8, As + ch * 512);
            GLL(wt + (size_t)(n0 + row) * 256 + k0 + ul * 8, Bs + ch * 512);
        }
        asm volatile("s_waitcnt vmcnt(0)" ::: "memory");
        __syncthreads();
        #pragma unroll
        for (int ks = 0; ks < 2; ++ks) {
            bf16x8 a[2], b[2];
            #pragma unroll
            for (int mf = 0; mf < 2; ++mf) {
                int row = mh + mf * 16 + (l & 15);
                int u   = (ks * 4 + (l >> 4)) ^ (row & 7);
                a[mf] = *(const bf16x8*)(As + row * 64 + u * 8);
            }
            #pragma unroll
            for (int nf = 0; nf < 2; ++nf) {
                int row = nh + nf * 16 + (l & 15);
                int u   = (ks * 4 + (l >> 4)) ^ (row & 7);
                b[nf] = *(const bf16x8*)(Bs + row * 64 + u * 8);
            }
            #pragma unroll
            for (int mf = 0; mf < 2; ++mf)
                #pragma unroll
                for (int nf = 0; nf < 2; ++nf)
                    acc[mf][nf] = __builtin_amdgcn_mfma_f32_16x16x32_bf16(
                        a[mf], b[nf], acc[mf][nf], 0, 0, 0);
        }
    }

    #pragma unroll
    for (int mf = 0; mf < 2; ++mf)
        #pragma unroll
        for (int nf = 0; nf < 2; ++nf)
            #pragma unroll
            for (int r = 0; r < 4; ++r) {
                int row = m0 + mh + mf * 16 + (l >> 4) * 4 + r;
                int col = n0 + nh + nf * 16 + (l & 15);
                float bias = (col < 256) ? bh[col] : (col < 288) ? bg[col - 256] : bfv[col - 288];
                u16 v = f2b(acc[mf][nf][r] + bias);
                if (col < 256)      h[(size_t)row * 256 + col] = v;
                else if (col < 288) g[(size_t)row * 32 + (col - 256)] = v;
                else                f[(size_t)row * 32 + (col - 288)] = v;
            }
}

// ---------------------------------------------------------------------------
// Kernel 2: transpose h [N,256] -> ht [256,N] (bf16)
// ---------------------------------------------------------------------------
__global__ __launch_bounds__(256) void transpose_kernel(
    const u16* __restrict__ h, u16* __restrict__ ht)
{
    __shared__ u16 tile[64][65];
    const int t = threadIdx.x;
    const int r0 = blockIdx.x * 64, c0 = blockIdx.y * 64;
    #pragma unroll
    for (int i = 0; i < 16; ++i) {
        int r = i * 4 + (t >> 6), c = t & 63;
        tile[r][c] = h[(size_t)(r0 + r) * 256 + c0 + c];
    }
    __syncthreads();
    #pragma unroll
    for (int i = 0; i < 16; ++i) {
        int c = i * 4 + (t >> 6), r = t & 63;
        ht[(size_t)(c0 + c) * N_TOK + r0 + r] = tile[r][c];
    }
}

// ---------------------------------------------------------------------------
// Kernel 3: flash attention, 32x32 MFMA, swapped QK^T, in-register softmax.
// 54 x NSPLIT blocks, 512 thr. wave w: qg=w>>1 (64 queries), cg=w&1 (128 ch).
// KT=32 keys/tile. K LDS [4 c8][32 key] 16B units; V^T LDS [256 ch][32 key],
// unit-XOR swizzled. Partial (O,m,l) per split; combined in kernel 4.
// ---------------------------------------------------------------------------
__global__ __launch_bounds__(512, 2) void attn_kernel(
    const u16* __restrict__ g, const u16* __restrict__ f, const u16* __restrict__ ht,
    u16* __restrict__ po, float* __restrict__ pm, float* __restrict__ pl)
{
    __shared__ u16 Vt[2][8192];        // 16KB each: [ch][32keys], unit swizzle
    __shared__ u16 Ks[2][1024];        // 2KB each:  [c8][key] 16B units
    __shared__ float rfs[8][2][32];

    const int t = threadIdx.x, l = t & 63, w = t >> 6;
    const int hi = l >> 5, l31 = l & 31;
    const int qg = w >> 1, cg = w & 1;
    const int q0 = blockIdx.x * 256;
    const int split = blockIdx.y;
    const int kbase = split * KEYS_PER_SPLIT;

    // ---- Q fragments (held in regs): B[k][q] layout: k = 16*ks + 8*hi + e ----
    bf16x8 qf[2][2];
    #pragma unroll
    for (int qs = 0; qs < 2; ++qs)
        #pragma unroll
        for (int ks = 0; ks < 2; ++ks)
            qf[qs][ks] = *(const bf16x8*)(g + (size_t)(q0 + qg * 64 + qs * 32 + l31) * 32
                                            + ks * 16 + hi * 8);

    f32x16 acc[2][4] = {};
    float m_run[2] = {-1e30f, -1e30f}, l_run[2] = {0.f, 0.f};

    // ---- precomputed staging source addresses (per-lane) ----
    const int u0 = w * 128 + l;
    const int ch0 = u0 >> 2,  ukg0 = (u0 & 3) ^ (ch0 & 3);
    const int u1 = u0 + 64;
    const int ch1 = u1 >> 2,  ukg1 = (u1 & 3) ^ (ch1 & 3);
    const u16* vsrc0 = ht + (size_t)ch0 * N_TOK + kbase + ukg0 * 8;
    const u16* vsrc1 = ht + (size_t)ch1 * N_TOK + kbase + ukg1 * 8;
    const int ku = w * 64 + l;                      // only w<2 uses
    const u16* ksrc = f + (size_t)(kbase + (ku & 31)) * 32 + (ku >> 5) * 8;

    auto stage = [&](int tile, int buf) {
        const int koff = tile * KT;
        GLL(vsrc0 + koff, Vt[buf] + (size_t)w * 128 * 8);
        GLL(vsrc1 + koff, Vt[buf] + (size_t)(w * 128 + 64) * 8);
        if (w < 2) GLL(ksrc + (size_t)koff * 32, Ks[buf] + (size_t)w * 64 * 8);
    };

    stage(0, 0);

    for (int tl = 0; tl < TILES_PER_SPLIT; ++tl) {
        const int buf = tl & 1;
        asm volatile("" ::: "memory");
        __builtin_amdgcn_s_barrier();               // all waves done reading buf^1
        asm volatile("" ::: "memory");
        stage(tl + 1 < TILES_PER_SPLIT ? tl + 1 : 0, buf ^ 1);
        if (w < 2) asm volatile("s_waitcnt vmcnt(3)" ::: "memory");
        else       asm volatile("s_waitcnt vmcnt(2)" ::: "memory");
        __builtin_amdgcn_s_barrier();               // tile tl staged by all waves
        asm volatile("" ::: "memory");

        // ---- K fragments: A[key][c]: key=l31, c = 16*ks + 8*hi + e ----
        bf16x8 kf[2];
        #pragma unroll
        for (int ks = 0; ks < 2; ++ks)
            kf[ks] = *(const bf16x8*)(Ks[buf] + ((ks * 2 + hi) * 32 + l31) * 8);

        // ---- S = K Q^T (swapped): D[key][q], col=q=l31, row=key(r,hi) ----
        f32x16 s[2];
        #pragma unroll
        for (int qs = 0; qs < 2; ++qs) {
            f32x16 z = {};
            z = __builtin_amdgcn_mfma_f32_32x32x16_bf16(kf[0], qf[qs][0], z, 0, 0, 0);
            s[qs] = __builtin_amdgcn_mfma_f32_32x32x16_bf16(kf[1], qf[qs][1], z, 0, 0, 0);
        }

        // ---- in-register online softmax + P fragment build ----
        unsigned pa[2][2][4];
        #pragma unroll
        for (int qs = 0; qs < 2; ++qs) {
            float mx = s[qs][0];
            #pragma unroll
            for (int r = 1; r < 16; ++r) mx = fmaxf(mx, s[qs][r]);
            float mrow = cross_max(mx);
            if (!__all(mrow <= m_run[qs] + 8.f)) {     // T13 defer-max
                float mnew = fmaxf(m_run[qs], mrow);
                float rf = __expf(m_run[qs] - mnew);
                m_run[qs] = mnew;
                l_run[qs] *= rf;
                if (hi == 0) rfs[w][qs][l31] = rf;
                asm volatile("s_waitcnt lgkmcnt(0)" ::: "memory");
                __builtin_amdgcn_sched_barrier(0);
                float4 rv[4];
                #pragma unroll
                for (int b = 0; b < 4; ++b)
                    rv[b] = *(const float4*)&rfs[w][qs][b * 8 + hi * 4];
                #pragma unroll
                for (int cht = 0; cht < 4; ++cht)
                    #pragma unroll
                    for (int r = 0; r < 16; ++r)
                        acc[qs][cht][r] *= rv[r >> 2][r & 3];
            }
            float pv[16], sum = 0.f;
            #pragma unroll
            for (int r = 0; r < 16; ++r) {
                pv[r] = __expf(s[qs][r] - m_run[qs]);
                sum += pv[r];
            }
            l_run[qs] += cross_sum(sum);
            #pragma unroll
            for (int ks = 0; ks < 2; ++ks) {
                const int o = ks * 8;
                unsigned a0 = cvtpk(pv[o + 0], pv[o + 1]);
                unsigned b0 = cvtpk(pv[o + 2], pv[o + 3]);
                unsigned a1 = cvtpk(pv[o + 4], pv[o + 5]);
                unsigned b1 = cvtpk(pv[o + 6], pv[o + 7]);
                asm volatile("v_permlane32_swap_b32 %0, %1" : "+v"(a1), "+v"(a0));
                asm volatile("v_permlane32_swap_b32 %0, %1" : "+v"(b1), "+v"(b0));
                pa[qs][ks][0] = a0; pa[qs][ks][1] = b0;
                pa[qs][ks][2] = a1; pa[qs][ks][3] = b1;
            }
        }

        // ---- PV: A = P (regs), B = V^T (LDS b128), V-frag reused for 2 qs ----
        __builtin_amdgcn_s_setprio(1);
        #pragma unroll
        for (int ks = 0; ks < 2; ++ks) {
            bf16x8 vf[4];
            #pragma unroll
            for (int cht = 0; cht < 4; ++cht) {
                int ch = cg * 128 + cht * 32 + l31;
                int swz = (ks * 2 + hi) ^ (ch & 3);
                vf[cht] = *(const bf16x8*)(Vt[buf] + ch * 32 + swz * 8);
            }
            #pragma unroll
            for (int cht = 0; cht < 4; ++cht)
                #pragma unroll
                for (int qs = 0; qs < 2; ++qs) {
                    union { unsigned u[4]; bf16x8 v; } pb;
                    pb.u[0] = pa[qs][ks][0]; pb.u[1] = pa[qs][ks][1];
                    pb.u[2] = pa[qs][ks][2]; pb.u[3] = pa[qs][ks][3];
                    acc[qs][cht] = __builtin_amdgcn_mfma_f32_32x32x16_bf16(
                        pb.v, vf[cht], acc[qs][cht], 0, 0, 0);
                }
        }
        __builtin_amdgcn_s_setprio(0);
    }

    // ---- epilogue: write unnormalized partial O (bf16) + m,l ----
    #pragma unroll
    for (int qs = 0; qs < 2; ++qs) {
        #pragma unroll
        for (int cht = 0; cht < 4; ++cht) {
            int ch = cg * 128 + cht * 32 + l31;
            #pragma unroll
            for (int r = 0; r < 16; ++r) {
                int qq = q0 + qg * 64 + qs * 32 + (r & 3) + 8 * (r >> 2) + 4 * hi;
                po[((size_t)split * N_TOK + qq) * 256 + ch] = f2b(acc[qs][cht][r]);
            }
        }
        if (hi == 0 && cg == 0) {
            int qq = q0 + qg * 64 + qs * 32 + l31;
            pm[(size_t)split * N_TOK + qq] = m_run[qs];
            pl[(size_t)split * N_TOK + qq] = l_run[qs];
        }
    }
}

// ---------------------------------------------------------------------------
// Kernel 4: combine split partials; out = gamma*(O/l) + x
// ---------------------------------------------------------------------------
__global__ __launch_bounds__(256) void combine_kernel(
    const u16* __restrict__ po, const float* __restrict__ pm, const float* __restrict__ pl,
    const float* __restrict__ x, const float* __restrict__ gamma, float* __restrict__ out)
{
    const int c = threadIdx.x;
    const float gm = gamma[c];
    for (int i = 0; i < 8; ++i) {
        const int q = blockIdx.x * 8 + i;
        float mv[NSPLIT], M = -1e30f;
        #pragma unroll
        for (int s = 0; s < NSPLIT; ++s) {
            mv[s] = pm[(size_t)s * N_TOK + q];
            M = fmaxf(M, mv[s]);
        }
        float lsum = 0.f, o = 0.f;
        #pragma unroll
        for (int s = 0; s < NSPLIT; ++s) {
            float wsc = __expf(mv[s] - M);
            lsum += wsc * pl[(size_t)s * N_TOK + q];
            o += wsc * b2f(po[((size_t)s * N_TOK + q) * 256 + c]);
        }
        size_t idx = (size_t)q * 256 + c;
        out[idx] = gm * (o / lsum) + x[idx];
    }
}

// ---------------------------------------------------------------------------
extern "C" void kernel_launch(void* const* d_in, const int* in_sizes, int n_in,
                              void* d_out, int out_size, void* d_ws, size_t ws_size,
                              hipStream_t stream) {
    const float* x     = (const float*)d_in[0];
    const float* wg    = (const float*)d_in[1];
    const float* bg    = (const float*)d_in[2];
    const float* wf    = (const float*)d_in[3];
    const float* bfv   = (const float*)d_in[4];
    const float* wh    = (const float*)d_in[5];
    const float* bh    = (const float*)d_in[6];
    const float* gamma = (const float*)d_in[7];
    float* out = (float*)d_out;

    u16* ws = (u16*)d_ws;
    u16* gq = ws;                                   // N*32
    u16* fk = gq + (size_t)N_TOK * 32;              // N*32
    u16* ht = fk + (size_t)N_TOK * 32;              // N*256
    u16* po = ht + (size_t)N_TOK * 256;             // NSPLIT*N*256 (overlays scratch A)
    u16* xb = po;                                   // scratch A: N*256
    u16* wt = xb + (size_t)N_TOK * 256;             // 320*256
    u16* hv = wt + 320 * 256;                       // N*256
    float* pm = (float*)(po + (size_t)NSPLIT * N_TOK * 256);
    float* pl = pm + (size_t)NSPLIT * N_TOK;

    prep_kernel<<<1728, 512, 0, stream>>>(x, wh, wg, wf, xb, wt);
    proj_kernel<<<dim3(216, 5), 256, 0, stream>>>(xb, wt, bg, bfv, bh, gq, fk, hv);
    transpose_kernel<<<dim3(216, 4), 256, 0, stream>>>(hv, ht);
    attn_kernel<<<dim3(54, NSPLIT), 512, 0, stream>>>(gq, fk, ht, po, pm, pl);
    combine_kernel<<<1728, 256, 0, stream>>>(po, pm, pl, x, gamma, out);
}